// Round 16
// baseline (64.072 us; speedup 1.0000x reference)
//
// RoutingFreeGate — v16: A operand global->registers with 1-step lookahead
// (dbl reg set, unroll-by-2); B stays gll16+LDS counted-vmcnt (v14/v15 loop).
// Rationale: v15 gemm was LDS-BW-bound (96 KiB/block-step ~= 1536cy/step).
// A-f32-in-LDS was half that traffic; removing it halves the LDS wall.
#include <hip/hip_runtime.h>
#include <hip/hip_bf16.h>
#include <math.h>

#define H_DIM 2048
#define R_DIM 512
#define NTOK  16384
#define BM    64
#define BN    128
#define BK    64
#define KST   (H_DIM / BK)           // 32
#define NEG_BIG (-1.0e30f)           // finite in f32 AND after bf16 rounding

typedef __attribute__((ext_vector_type(8))) short bf16x8;
typedef __attribute__((ext_vector_type(4))) float f32x4;

static __device__ __forceinline__ unsigned short f2bf(float f) {
    __hip_bfloat16 h = __float2bfloat16(f);   // RNE
    return *reinterpret_cast<unsigned short*>(&h);
}

static __device__ __forceinline__ bf16x8 pack8(float4 lo, float4 hi) {
    union { bf16x8 v; unsigned short u[8]; } t;
    t.u[0] = f2bf(lo.x); t.u[1] = f2bf(lo.y); t.u[2] = f2bf(lo.z); t.u[3] = f2bf(lo.w);
    t.u[4] = f2bf(hi.x); t.u[5] = f2bf(hi.y); t.u[6] = f2bf(hi.z); t.u[7] = f2bf(hi.w);
    return t.v;
}

static __device__ __forceinline__ void gll16(const void* g, void* l) {
    __builtin_amdgcn_global_load_lds(
        (const __attribute__((address_space(1))) unsigned int*)g,
        (__attribute__((address_space(3))) unsigned int*)l,
        16, 0, 0);
}

// ---------------------------------------------------------------------------
// Aux: blocks 0-127 wcvt (W -> bf16 K-major Wb), block 128 scan (mask ->
// vidx/nv). (Unchanged from v15.)
// ---------------------------------------------------------------------------
__global__ __launch_bounds__(1024) void rfg16_aux(
    const float* __restrict__ W, unsigned short* __restrict__ Wb,
    const unsigned char* __restrict__ msk,
    int* __restrict__ vidx, int* __restrict__ nv_out)
{
    __shared__ int Wt[16];
    __shared__ int Wbase[16];
    const int b   = blockIdx.x;
    const int tid = threadIdx.x;

    if (b < 128) {
        const int i  = b * 1024 + tid;       // 0..131071
        const int r  = i >> 8;               // 0..511
        const int k8 = i & 255;              // 0..255
        const float* src = W + (size_t)r * H_DIM + k8 * 8;
        float4 a = *reinterpret_cast<const float4*>(src);
        float4 c = *reinterpret_cast<const float4*>(src + 4);
        *reinterpret_cast<bf16x8*>(Wb + ((size_t)k8 * R_DIM + r) * 8) = pack8(a, c);
    } else {
        const int lane = tid & 63;
        const int wv   = tid >> 6;
        union { uint4 v; unsigned char c[16]; } u;
        u.v = *reinterpret_cast<const uint4*>(msk + tid * 16);
        const unsigned int s4 = u.v.x + u.v.y + u.v.z + u.v.w;  // bytes<=4
        const int cnt = (s4 & 0xFF) + ((s4 >> 8) & 0xFF)
                      + ((s4 >> 16) & 0xFF) + (s4 >> 24);
        int pfx = cnt;
        #pragma unroll
        for (int off = 1; off < 64; off <<= 1) {
            const int t = __shfl_up(pfx, off, 64);
            if (lane >= off) pfx += t;
        }
        if (lane == 63) Wt[wv] = pfx;
        __syncthreads();
        if (tid == 0) {
            int run = 0;
            for (int i = 0; i < 16; ++i) { Wbase[i] = run; run += Wt[i]; }
        }
        __syncthreads();
        int p = Wbase[wv] + pfx - cnt;
        #pragma unroll
        for (int j = 0; j < 16; ++j)
            if (u.c[j]) vidx[p++] = tid * 16 + j;
        if (tid == 1023) {
            const int total = Wbase[15] + Wt[15];
            nv_out[0] = total;
            const int pe = (total + 63) & ~63;
            for (int i = total; i < pe; ++i) vidx[i] = 0;
        }
    }
}

// ---------------------------------------------------------------------------
// Compacted GEMM 64x128, BK=64, 256 thr / 4 waves (2x2 of 32x64), acc[2][4].
// A: global->reg, one-step lookahead (Aa/Ab, unroll-by-2); compiler-inserted
// waitcnt covers A-reg readiness. B: gll16 into LDS dbuf, counted vmcnt(12)
// (outstanding = A(ks) 8 + B(ks+1) 4). Inactive blocks zero invalid rows.
// ---------------------------------------------------------------------------
__global__ __launch_bounds__(256, 2) void rfg16_gemm(
    const float* __restrict__ x,
    const unsigned char* __restrict__ msk,
    const unsigned short* __restrict__ Wb,
    const int* __restrict__ vidx,
    const int* __restrict__ nvp,
    float* __restrict__ part,            // [4][NTOK] sumsq partials
    float* __restrict__ hid)
{
    __shared__ __align__(16) short Bs[2][1024][8];  // [buf][k8*128+col][8] 32K
    __shared__ float Ps[2][BM];
    __shared__ int   Vr[BM];
    __shared__ int   Vv[BM];

    const int nv  = nvp[0];
    const int tid = threadIdx.x;
    // XCD swizzle: 4 n-tiles of an m-panel -> same XCD (A panel L2-shared).
    const int bid   = blockIdx.x;            // 1024 blocks
    const int xcd   = bid & 7;
    const int local = bid >> 3;              // 0..127
    const int nt    = local & 3;
    const int mt    = (local >> 2) * 8 + xcd;  // bijective 0..255
    const int m0    = mt * BM;

    if (m0 >= nv) {
        // ---- inactive block: zero invalid hidden rows (grid-stride) ----
        const int mt_min = (nv + 63) >> 6;
        const int Z = (256 - mt_min) * 4;            // # inactive blocks
        const int z = (mt - mt_min) * 4 + nt;        // ordinal in [0, Z)
        const float2 z2 = make_float2(0.f, 0.f);
        for (int t = z; t < NTOK; t += Z)
            if (!msk[t])
                *reinterpret_cast<float2*>(&hid[(size_t)t * R_DIM + tid * 2]) = z2;
        return;
    }
    const int n0 = nt * BN;

    const int w  = tid >> 6;
    const int l  = tid & 63;
    const int wr = w >> 1;               // 0..1: 32-row group
    const int wc = w & 1;                // 0..1: 64-col group
    const int fr = l & 15;
    const int fg = l >> 4;               // k-subgroup 0..3

    // per-lane gathered A row bases (A frag: row=(l&15), k=(l>>4)*8)
    const float* pA[2];
    pA[0] = x + (size_t)vidx[m0 + wr * 32 + fr]      * H_DIM + fg * 8;
    pA[1] = x + (size_t)vidx[m0 + wr * 32 + 16 + fr] * H_DIM + fg * 8;
    if (tid < BM) {
        Vr[tid] = vidx[m0 + tid];
        Vv[tid] = (m0 + tid) < nv;
    }

    f32x4 acc[2][4] = {};
    float4 Aa[2][2][2], Ab[2][2][2];     // [mi][kk][lo/hi], const-indexed only

#define RFG16_STAGEB(ks_, buf_) do {                                     \
        _Pragma("unroll")                                                \
        for (int j = 0; j < 4; ++j) {                                    \
            const int idx = j * 256 + tid;                               \
            const int k8 = idx >> 7, col = idx & 127;                    \
            gll16(Wb + ((size_t)((ks_) * 8 + k8) * R_DIM + n0 + col) * 8,\
                  (char*)&Bs[buf_][0][0] + idx * 16);                    \
        }                                                                \
    } while (0)

#define RFG16_LOADA(ks_, D) do {                                         \
        _Pragma("unroll")                                                \
        for (int mi = 0; mi < 2; ++mi)                                   \
            _Pragma("unroll")                                            \
            for (int kk = 0; kk < 2; ++kk) {                             \
                const float* _p = pA[mi] + (ks_) * BK + kk * 32;         \
                D[mi][kk][0] = *reinterpret_cast<const float4*>(_p);     \
                D[mi][kk][1] = *reinterpret_cast<const float4*>(_p + 4); \
            }                                                            \
    } while (0)

    // STEP: vmcnt -> barrier -> issue A(ks+1) -> B ds_reads -> lgkm0 ->
    // barrier -> stage B(ks+2) -> pack A (compiler waits A(ks)) -> 16 MFMA.
#define RFG16_STEP(ks_, buf_, Duse, Dload, loadA_, stage_, VM) do {      \
        asm volatile("s_waitcnt vmcnt(" VM ")" ::: "memory");            \
        __builtin_amdgcn_s_barrier();                                    \
        if (loadA_) RFG16_LOADA((ks_) + 1, Dload);                       \
        bf16x8 bfr[2][4];                                                \
        _Pragma("unroll")                                                \
        for (int kk = 0; kk < 2; ++kk)                                   \
            _Pragma("unroll")                                            \
            for (int ni = 0; ni < 4; ++ni)                               \
                bfr[kk][ni] = *reinterpret_cast<const bf16x8*>(          \
                    &Bs[buf_][(kk * 4 + fg) * 128 + wc * 64 + ni * 16 + fr][0]); \
        asm volatile("s_waitcnt lgkmcnt(0)" ::: "memory");               \
        __builtin_amdgcn_s_barrier();     /* all waves done reading buf */ \
        if (stage_) RFG16_STAGEB((ks_) + 2, buf_);                       \
        bf16x8 afr[2][2];                                                \
        _Pragma("unroll")                                                \
        for (int mi = 0; mi < 2; ++mi)                                   \
            _Pragma("unroll")                                            \
            for (int kk = 0; kk < 2; ++kk)                               \
                afr[mi][kk] = pack8(Duse[mi][kk][0], Duse[mi][kk][1]);   \
        __builtin_amdgcn_s_setprio(1);                                   \
        _Pragma("unroll")                                                \
        for (int kk = 0; kk < 2; ++kk)                                   \
            _Pragma("unroll")                                            \
            for (int mi = 0; mi < 2; ++mi)                               \
                _Pragma("unroll")                                        \
                for (int ni = 0; ni < 4; ++ni)                           \
                    acc[mi][ni] = __builtin_amdgcn_mfma_f32_16x16x32_bf16(\
                        afr[mi][kk], bfr[kk][ni], acc[mi][ni], 0, 0, 0); \
        __builtin_amdgcn_s_setprio(0);                                   \
    } while (0)

    // prologue: queue order B(0)[4], A(0)[8], B(1)[4]
    RFG16_STAGEB(0, 0);
    RFG16_LOADA(0, Aa);
    RFG16_STAGEB(1, 1);

    for (int kb = 0; kb < KST - 2; kb += 2) {    // 0..29
        RFG16_STEP(kb,     0, Aa, Ab, true, true, "12");
        RFG16_STEP(kb + 1, 1, Ab, Aa, true, true, "12");
    }
    RFG16_STEP(KST - 2, 0, Aa, Ab, true,  false, "12");  // ks=30
    RFG16_STEP(KST - 1, 1, Ab, Aa, false, false, "0");   // ks=31

#undef RFG16_STEP
#undef RFG16_LOADA
#undef RFG16_STAGEB

    // ---- epilogue: norm partials, scattered C write ----
    #pragma unroll
    for (int mi = 0; mi < 2; ++mi) {
        #pragma unroll
        for (int r = 0; r < 4; ++r) {
            const int rowl = wr * 32 + mi * 16 + fg * 4 + r;
            float s = 0.0f;
            #pragma unroll
            for (int ni = 0; ni < 4; ++ni) {
                const float v = acc[mi][ni][r];
                s = fmaf(v, v, s);
            }
            #pragma unroll
            for (int off = 1; off < 16; off <<= 1)
                s += __shfl_xor(s, off, 64);
            if (fr == 0) Ps[wc][rowl] = s;
        }
    }

    #pragma unroll
    for (int mi = 0; mi < 2; ++mi)
        #pragma unroll
        for (int ni = 0; ni < 4; ++ni)
            #pragma unroll
            for (int r = 0; r < 4; ++r) {
                const int rowl = wr * 32 + mi * 16 + fg * 4 + r;
                if (Vv[rowl])
                    hid[(size_t)Vr[rowl] * R_DIM + n0 + wc * 64 + ni * 16 + fr] =
                        acc[mi][ni][r];
            }

    __syncthreads();
    if (tid < BM && Vv[tid])
        part[(size_t)nt * NTOK + Vr[tid]] = Ps[0][tid] + Ps[1][tid];
}

// ---------------------------------------------------------------------------
// Finish: sum the 4 n-tile partials, sqrt/scale/bias, gate. Unwritten part
// slots (invalid tokens) may hold garbage: nan-clamp + msk gate handle it.
// ---------------------------------------------------------------------------
__global__ __launch_bounds__(256) void rfg16_score(
    const unsigned char* __restrict__ msk,
    const float* __restrict__ gsc,
    const float* __restrict__ gbi,
    const float* __restrict__ part,
    float* __restrict__ om,
    float* __restrict__ os)
{
    const int t = blockIdx.x * 256 + threadIdx.x;
    const float s = part[t] + part[NTOK + t] + part[2 * NTOK + t] + part[3 * NTOK + t];
    float sc = sqrtf(s) * gsc[0] - gbi[0];
    if (!(sc > -1.0e30f && sc < 1.0e30f)) sc = 0.0f;  // never emit inf/nan
    const bool keep = (msk[t] != 0) && (sc >= 0.5f);
    om[t] = keep ? 1.0f : 0.0f;
    os[t] = keep ? sc : NEG_BIG;
}

extern "C" void kernel_launch(void* const* d_in, const int* in_sizes, int n_in,
                              void* d_out, int out_size, void* d_ws, size_t ws_size,
                              hipStream_t stream)
{
    const float*         x     = (const float*)d_in[0];
    const unsigned char* msk   = (const unsigned char*)d_in[1];  // jax bool = 1B
    const float*         W     = (const float*)d_in[2];
    const float*         scale = (const float*)d_in[3];
    const float*         bias  = (const float*)d_in[4];

    float* out = (float*)d_out;
    float* om  = out;               // [NTOK]
    float* os  = out + NTOK;        // [NTOK]
    float* hid = out + 2 * NTOK;    // [NTOK][R_DIM]

    char* ws = (char*)d_ws;
    unsigned short* Wb   = (unsigned short*)ws;                       // 2 MiB
    float*          part = (float*)(ws + 2 * 1024 * 1024);            // 256 KiB
    int*            vidx = (int*)(ws + 2 * 1024 * 1024 + 256 * 1024); // 64 KiB
    int*            nvp  = (int*)(ws + 2 * 1024 * 1024 + 320 * 1024); // 4 B

    rfg16_aux<<<129, 1024, 0, stream>>>(W, Wb, msk, vidx, nvp);
    rfg16_gemm<<<(NTOK / BM) * (R_DIM / BN), 256, 0, stream>>>(
        x, msk, Wb, vidx, nvp, part, hid);
    rfg16_score<<<NTOK / 256, 256, 0, stream>>>(msk, scale, bias, part, om, os);
}

// Round 18
// 45.117 us; speedup vs baseline: 1.4201x; 1.4201x over previous
//
// RoutingFreeGate — v18: v15 + A stored bf16 in LDS via reg-staged cvt, made
// race-proof: QUAD-buffered A (write target's last reader is 2 steps back),
// sched_barrier(0) fences after every waitcnt/barrier (rule #18: s_barrier
// is not a compiler memory fence), 2-step A-glb lead, bank-swizzled A layout.
// B path (gll16 dbuf) and epilogue identical to v15 (known good).
#include <hip/hip_runtime.h>
#include <hip/hip_bf16.h>
#include <math.h>

#define H_DIM 2048
#define R_DIM 512
#define NTOK  16384
#define BM    64
#define BN    128
#define BK    64
#define KST   (H_DIM / BK)           // 32
#define NEG_BIG (-1.0e30f)           // finite in f32 AND after bf16 rounding

typedef __attribute__((ext_vector_type(8))) short bf16x8;
typedef __attribute__((ext_vector_type(4))) float f32x4;

static __device__ __forceinline__ unsigned short f2bf(float f) {
    __hip_bfloat16 h = __float2bfloat16(f);   // RNE
    return *reinterpret_cast<unsigned short*>(&h);
}

static __device__ __forceinline__ bf16x8 pack8(float4 lo, float4 hi) {
    union { bf16x8 v; unsigned short u[8]; } t;
    t.u[0] = f2bf(lo.x); t.u[1] = f2bf(lo.y); t.u[2] = f2bf(lo.z); t.u[3] = f2bf(lo.w);
    t.u[4] = f2bf(hi.x); t.u[5] = f2bf(hi.y); t.u[6] = f2bf(hi.z); t.u[7] = f2bf(hi.w);
    return t.v;
}

static __device__ __forceinline__ void gll16(const void* g, void* l) {
    __builtin_amdgcn_global_load_lds(
        (const __attribute__((address_space(1))) unsigned int*)g,
        (__attribute__((address_space(3))) unsigned int*)l,
        16, 0, 0);
}

// ---------------------------------------------------------------------------
// Aux: blocks 0-127 wcvt (W -> bf16 K-major Wb), block 128 scan (mask ->
// vidx/nv). (Unchanged from v15.)
// ---------------------------------------------------------------------------
__global__ __launch_bounds__(1024) void rfg18_aux(
    const float* __restrict__ W, unsigned short* __restrict__ Wb,
    const unsigned char* __restrict__ msk,
    int* __restrict__ vidx, int* __restrict__ nv_out)
{
    __shared__ int Wt[16];
    __shared__ int Wbase[16];
    const int b   = blockIdx.x;
    const int tid = threadIdx.x;

    if (b < 128) {
        const int i  = b * 1024 + tid;       // 0..131071
        const int r  = i >> 8;               // 0..511
        const int k8 = i & 255;              // 0..255
        const float* src = W + (size_t)r * H_DIM + k8 * 8;
        float4 a = *reinterpret_cast<const float4*>(src);
        float4 c = *reinterpret_cast<const float4*>(src + 4);
        *reinterpret_cast<bf16x8*>(Wb + ((size_t)k8 * R_DIM + r) * 8) = pack8(a, c);
    } else {
        const int lane = tid & 63;
        const int wv   = tid >> 6;
        union { uint4 v; unsigned char c[16]; } u;
        u.v = *reinterpret_cast<const uint4*>(msk + tid * 16);
        const unsigned int s4 = u.v.x + u.v.y + u.v.z + u.v.w;  // bytes<=4
        const int cnt = (s4 & 0xFF) + ((s4 >> 8) & 0xFF)
                      + ((s4 >> 16) & 0xFF) + (s4 >> 24);
        int pfx = cnt;
        #pragma unroll
        for (int off = 1; off < 64; off <<= 1) {
            const int t = __shfl_up(pfx, off, 64);
            if (lane >= off) pfx += t;
        }
        if (lane == 63) Wt[wv] = pfx;
        __syncthreads();
        if (tid == 0) {
            int run = 0;
            for (int i = 0; i < 16; ++i) { Wbase[i] = run; run += Wt[i]; }
        }
        __syncthreads();
        int p = Wbase[wv] + pfx - cnt;
        #pragma unroll
        for (int j = 0; j < 16; ++j)
            if (u.c[j]) vidx[p++] = tid * 16 + j;
        if (tid == 1023) {
            const int total = Wbase[15] + Wt[15];
            nv_out[0] = total;
            const int pe = (total + 63) & ~63;
            for (int i = total; i < pe; ++i) vidx[i] = 0;
        }
    }
}

// ---------------------------------------------------------------------------
// Compacted GEMM 64x128, BK=64, 256 thr / 4 waves (2x2 of 32x64), acc[2][4].
// A: global->reg (64B/thread, 2-step lead) -> f2bf -> ds_write into QUAD-
// buffered swizzled LDS [abuf][row][k8^(row&7)]. B: gll16 dbuf (v15).
// vmcnt ledger: steady 8 issues/step; steady VM=8, tail 8/4/4/0.
// ---------------------------------------------------------------------------
__global__ __launch_bounds__(256, 2) void rfg18_gemm(
    const float* __restrict__ x,
    const unsigned char* __restrict__ msk,
    const unsigned short* __restrict__ Wb,
    const int* __restrict__ vidx,
    const int* __restrict__ nvp,
    float* __restrict__ part,            // [4][NTOK] sumsq partials
    float* __restrict__ hid)
{
    __shared__ __align__(16) short Asb[4][64][8][8];  // [abuf][row][k8][8] 32K
    __shared__ __align__(16) short Bs[2][1024][8];    // [bbuf][k8*128+col] 32K
    __shared__ float Ps[2][BM];
    __shared__ int   Vr[BM];
    __shared__ int   Vv[BM];

    const int nv  = nvp[0];
    const int tid = threadIdx.x;
    // XCD swizzle: 4 n-tiles of an m-panel -> same XCD.
    const int bid   = blockIdx.x;            // 1024 blocks
    const int xcd   = bid & 7;
    const int local = bid >> 3;              // 0..127
    const int nt    = local & 3;
    const int mt    = (local >> 2) * 8 + xcd;  // bijective 0..255
    const int m0    = mt * BM;

    if (m0 >= nv) {
        // ---- inactive block: zero invalid hidden rows (grid-stride) ----
        const int mt_min = (nv + 63) >> 6;
        const int Z = (256 - mt_min) * 4;            // # inactive blocks
        const int z = (mt - mt_min) * 4 + nt;        // ordinal in [0, Z)
        const float2 z2 = make_float2(0.f, 0.f);
        for (int t = z; t < NTOK; t += Z)
            if (!msk[t])
                *reinterpret_cast<float2*>(&hid[(size_t)t * R_DIM + tid * 2]) = z2;
        return;
    }
    const int n0 = nt * BN;

    const int w  = tid >> 6;
    const int l  = tid & 63;
    const int wr = w >> 1;               // 0..1: 32-row group
    const int wc = w & 1;                // 0..1: 64-col group
    const int fr = l & 15;
    const int fg = l >> 4;               // k-subgroup 0..3

    // A staging map: thread t -> row t>>2, k-chunk (t&3)*16 floats (64 B)
    const int ar = tid >> 2;
    const int kc = tid & 3;
    const float* gAx = x + (size_t)vidx[m0 + ar] * H_DIM + kc * 16;
    if (tid < BM) {
        Vr[tid] = vidx[m0 + tid];
        Vv[tid] = (m0 + tid) < nv;
    }

    f32x4 acc[2][4] = {};
    float4 Ga[4], Gb[4];                 // A-glb sets, 2-step lead, static idx

#define RFG18_LOADA(ks_, G) do {                                         \
        const float* _p = gAx + (ks_) * BK;                              \
        G[0] = *reinterpret_cast<const float4*>(_p);                     \
        G[1] = *reinterpret_cast<const float4*>(_p + 4);                 \
        G[2] = *reinterpret_cast<const float4*>(_p + 8);                 \
        G[3] = *reinterpret_cast<const float4*>(_p + 12);                \
    } while (0)

    // swizzled A write: k8 index XOR row&7 (bank-spread, read uses same XOR)
#define RFG18_CVTW(G, ab_) do {                                          \
        *reinterpret_cast<bf16x8*>(&Asb[ab_][ar][(kc * 2)     ^ (ar & 7)][0]) = pack8(G[0], G[1]); \
        *reinterpret_cast<bf16x8*>(&Asb[ab_][ar][(kc * 2 + 1) ^ (ar & 7)][0]) = pack8(G[2], G[3]); \
    } while (0)

#define RFG18_STAGEB(ks_, bb_) do {                                      \
        _Pragma("unroll")                                                \
        for (int j = 0; j < 4; ++j) {                                    \
            const int idx = j * 256 + tid;                               \
            const int k8 = idx >> 7, col = idx & 127;                    \
            gll16(Wb + ((size_t)((ks_) * 8 + k8) * R_DIM + n0 + col) * 8,\
                  (char*)&Bs[bb_][0][0] + idx * 16);                     \
        }                                                                \
    } while (0)

    // STEP: vmcnt(VM) |fence| barrier |fence| ds_reads -> lgkm0 |fence|
    //       barrier |fence| [CVTW A(ks+2)->abuf+2][LOADA(ks+4)][STAGEB(ks+2)]
    //       -> 16 MFMA. Write target abuf+2 was last READ at step ks-2.
#define RFG18_STEP(ks_, ab_, bb_, Gu, cvt_, glb_, stgB_, VM) do {        \
        asm volatile("s_waitcnt vmcnt(" VM ")" ::: "memory");            \
        __builtin_amdgcn_sched_barrier(0);                               \
        __builtin_amdgcn_s_barrier();                                    \
        __builtin_amdgcn_sched_barrier(0);                               \
        bf16x8 bfr[2][4];                                                \
        _Pragma("unroll")                                                \
        for (int kk = 0; kk < 2; ++kk)                                   \
            _Pragma("unroll")                                            \
            for (int ni = 0; ni < 4; ++ni)                               \
                bfr[kk][ni] = *reinterpret_cast<const bf16x8*>(          \
                    &Bs[bb_][(kk * 4 + fg) * 128 + wc * 64 + ni * 16 + fr][0]); \
        bf16x8 afr[2][2];                                                \
        _Pragma("unroll")                                                \
        for (int mi = 0; mi < 2; ++mi) {                                 \
            const int row = wr * 32 + mi * 16 + fr;                      \
            _Pragma("unroll")                                            \
            for (int kk = 0; kk < 2; ++kk)                               \
                afr[mi][kk] = *reinterpret_cast<const bf16x8*>(          \
                    &Asb[ab_][row][(kk * 4 + fg) ^ (row & 7)][0]);       \
        }                                                                \
        asm volatile("s_waitcnt lgkmcnt(0)" ::: "memory");               \
        __builtin_amdgcn_sched_barrier(0);                               \
        __builtin_amdgcn_s_barrier();                                    \
        __builtin_amdgcn_sched_barrier(0);                               \
        if (cvt_)  RFG18_CVTW(Gu, ((ab_) + 2) & 3);                      \
        if (glb_)  RFG18_LOADA((ks_) + 4, Gu);                           \
        if (stgB_) RFG18_STAGEB((ks_) + 2, bb_);                         \
        __builtin_amdgcn_s_setprio(1);                                   \
        _Pragma("unroll")                                                \
        for (int kk = 0; kk < 2; ++kk)                                   \
            _Pragma("unroll")                                            \
            for (int mi = 0; mi < 2; ++mi)                               \
                _Pragma("unroll")                                        \
                for (int ni = 0; ni < 4; ++ni)                           \
                    acc[mi][ni] = __builtin_amdgcn_mfma_f32_16x16x32_bf16(\
                        afr[mi][kk], bfr[kk][ni], acc[mi][ni], 0, 0, 0); \
        __builtin_amdgcn_s_setprio(0);                                   \
    } while (0)

    // prologue: A(0)->buf0, A(1)->buf1; B(0),B(1) staged; A(2),A(3) in regs
    RFG18_LOADA(0, Ga);
    RFG18_LOADA(1, Gb);
    RFG18_CVTW(Ga, 0);
    RFG18_CVTW(Gb, 1);
    RFG18_STAGEB(0, 0);
    RFG18_STAGEB(1, 1);
    RFG18_LOADA(2, Ga);
    RFG18_LOADA(3, Gb);
    asm volatile("s_waitcnt lgkmcnt(0)" ::: "memory");
    __builtin_amdgcn_sched_barrier(0);

    for (int kb = 0; kb < KST - 4; kb += 4) {    // steps 0..27
        RFG18_STEP(kb + 0, 0, 0, Ga, true, true, true, "8");
        RFG18_STEP(kb + 1, 1, 1, Gb, true, true, true, "8");
        RFG18_STEP(kb + 2, 2, 0, Ga, true, true, true, "8");
        RFG18_STEP(kb + 3, 3, 1, Gb, true, true, true, "8");
    }
    RFG18_STEP(KST - 4, 0, 0, Ga, true,  false, true,  "8");  // 28: cvt A30
    RFG18_STEP(KST - 3, 1, 1, Gb, true,  false, true,  "4");  // 29: cvt A31
    RFG18_STEP(KST - 2, 2, 0, Ga, false, false, false, "4");  // 30
    RFG18_STEP(KST - 1, 3, 1, Gb, false, false, false, "0");  // 31

#undef RFG18_STEP
#undef RFG18_STAGEB
#undef RFG18_CVTW
#undef RFG18_LOADA

    // ---- epilogue: norm partials, scattered C write ----
    #pragma unroll
    for (int mi = 0; mi < 2; ++mi) {
        #pragma unroll
        for (int r = 0; r < 4; ++r) {
            const int rowl = wr * 32 + mi * 16 + fg * 4 + r;
            float s = 0.0f;
            #pragma unroll
            for (int ni = 0; ni < 4; ++ni) {
                const float v = acc[mi][ni][r];
                s = fmaf(v, v, s);
            }
            #pragma unroll
            for (int off = 1; off < 16; off <<= 1)
                s += __shfl_xor(s, off, 64);
            if (fr == 0) Ps[wc][rowl] = s;
        }
    }

    #pragma unroll
    for (int mi = 0; mi < 2; ++mi)
        #pragma unroll
        for (int ni = 0; ni < 4; ++ni)
            #pragma unroll
            for (int r = 0; r < 4; ++r) {
                const int rowl = wr * 32 + mi * 16 + fg * 4 + r;
                if (Vv[rowl])
                    hid[(size_t)Vr[rowl] * R_DIM + n0 + wc * 64 + ni * 16 + fr] =
                        acc[mi][ni][r];
            }

    __syncthreads();
    if (tid < BM && Vv[tid])
        part[(size_t)nt * NTOK + Vr[tid]] = Ps[0][tid] + Ps[1][tid];
}

// ---------------------------------------------------------------------------
// Finish: sum the 4 n-tile partials, sqrt/scale/bias, gate. Unwritten part
// slots (invalid tokens) may hold garbage: nan-clamp + msk gate handle it.
// ---------------------------------------------------------------------------
__global__ __launch_bounds__(256) void rfg18_score(
    const unsigned char* __restrict__ msk,
    const float* __restrict__ gsc,
    const float* __restrict__ gbi,
    const float* __restrict__ part,
    float* __restrict__ om,
    float* __restrict__ os)
{
    const int t = blockIdx.x * 256 + threadIdx.x;
    const float s = part[t] + part[NTOK + t] + part[2 * NTOK + t] + part[3 * NTOK + t];
    float sc = sqrtf(s) * gsc[0] - gbi[0];
    if (!(sc > -1.0e30f && sc < 1.0e30f)) sc = 0.0f;  // never emit inf/nan
    const bool keep = (msk[t] != 0) && (sc >= 0.5f);
    om[t] = keep ? 1.0f : 0.0f;
    os[t] = keep ? sc : NEG_BIG;
}

extern "C" void kernel_launch(void* const* d_in, const int* in_sizes, int n_in,
                              void* d_out, int out_size, void* d_ws, size_t ws_size,
                              hipStream_t stream)
{
    const float*         x     = (const float*)d_in[0];
    const unsigned char* msk   = (const unsigned char*)d_in[1];  // jax bool = 1B
    const float*         W     = (const float*)d_in[2];
    const float*         scale = (const float*)d_in[3];
    const float*         bias  = (const float*)d_in[4];

    float* out = (float*)d_out;
    float* om  = out;               // [NTOK]
    float* os  = out + NTOK;        // [NTOK]
    float* hid = out + 2 * NTOK;    // [NTOK][R_DIM]

    char* ws = (char*)d_ws;
    unsigned short* Wb   = (unsigned short*)ws;                       // 2 MiB
    float*          part = (float*)(ws + 2 * 1024 * 1024);            // 256 KiB
    int*            vidx = (int*)(ws + 2 * 1024 * 1024 + 256 * 1024); // 64 KiB
    int*            nvp  = (int*)(ws + 2 * 1024 * 1024 + 320 * 1024); // 4 B

    rfg18_aux<<<129, 1024, 0, stream>>>(W, Wb, msk, vidx, nvp);
    rfg18_gemm<<<(NTOK / BM) * (R_DIM / BN), 256, 0, stream>>>(
        x, msk, Wb, vidx, nvp, part, hid);
    rfg18_score<<<NTOK / 256, 256, 0, stream>>>(msk, scale, bias, part, om, os);
}